// Round 5
// baseline (83.582 us; speedup 1.0000x reference)
//
#include <hip/hip_runtime.h>

#define B_    16
#define L_    512
#define N_    64
#define D_    256
#define T_    16                 // outputs per thread / chunk length
#define NT    (L_ / T_)          // 32 tiles per batch
#define KROWS (L_ + T_)          // 528 rows: tau = row-16, rows 0..15 zero
#define RING  8                  // K prefetch depth (K is L2-hot, ~200cy)
#define GUARD RING               // guard rows below Kpad row 0

// ---------------------------------------------------------------------------
// Kernel A: Kpad[row][d] = sum_n Re( (P[n,d]) * (dt*B[n]) * a[n]^tau ), tau=row-16
// ---------------------------------------------------------------------------
__global__ __launch_bounds__(256)
void build_K(const float* __restrict__ Lre_p, const float* __restrict__ Lim_p,
             const float* __restrict__ Bre_p, const float* __restrict__ Bim_p,
             const float* __restrict__ Pre_p, const float* __restrict__ Pim_p,
             const float* __restrict__ logdt_p,
             float* __restrict__ Kpad)   // points at row 0 (after guard)
{
    __shared__ float U[N_], V[N_];
    const int row = blockIdx.x;          // 0..KROWS-1
    const int tau = row - T_;
    const int d   = threadIdx.x;

    if (tau < 0) {                        // uniform per block
        Kpad[row * D_ + d] = 0.f;
        return;
    }

    const float dt = expf(logdt_p[0]);
    if (d < N_) {
        const float Lre = Lre_p[d], Lim = Lim_p[d];
        const float eL  = expf(Lre);
        const float wre = -eL * cosf(Lim);
        const float wim = -eL * sinf(Lim);
        const float ft  = (float)tau;
        const float er  = expf(ft * dt * wre);      // |a|^tau
        float sn, cs;
        sincosf(ft * dt * wim, &sn, &cs);
        const float Ar = er * cs, Ai = er * sn;     // a^tau
        const float Bdre = dt * Bre_p[d], Bdim = dt * Bim_p[d];
        U[d] = Bdre * Ar - Bdim * Ai;
        V[d] = Bdim * Ar + Bdre * Ai;
    }
    __syncthreads();

    float acc = 0.f;
    #pragma unroll 8
    for (int n = 0; n < N_; ++n)
        acc = fmaf(Pre_p[n * D_ + d], U[n],
              fmaf(-Pim_p[n * D_ + d], V[n], acc));
    Kpad[row * D_ + d] = acc;
}

// ---------------------------------------------------------------------------
// Kernel B: causal FIR. 512 threads = 2 history-halves x 256 channels.
// K: rolling 16-reg window + 8-deep register ring (L2-hot).
// u: double-buffered LDS chunks (16 steps x 256 d = 16 KB), float4 staged,
//    loads for chunk c+1 issued before computing chunk c (latency hidden).
// ---------------------------------------------------------------------------
__global__ __launch_bounds__(512, 4)
void conv_fir(const float* __restrict__ u, const float* __restrict__ Kpad,
              float* __restrict__ y)      // Kpad points at row 0 (after guard)
{
    __shared__ __align__(16) float smem[16384];   // 64 KB: 4 stage bufs x 4096

    const int g  = blockIdx.x;                 // 0..511 (all resident: 2/CU)
    const int b  = g & (B_ - 1);
    const int kk = g >> 4;                     // 0..31
    const int h  = threadIdx.x >> 8;           // history half 0/1 (wave-uniform)
    const int d  = threadIdx.x & (D_ - 1);

    const int C    = kk + 1;                   // 16-step chunks total
    const int c0   = (h * C) >> 1;             // this half's chunk range
    const int c1   = ((h + 1) * C) >> 1;
    const int Cmax = (C + 1) >> 1;             // common loop count
    const int sA   = c0 * T_;
    const int r0   = T_ * kk + T_;             // K row entering at s=0

    const float* ub = u + ((size_t)b * L_) * D_;              // [s][d]
    const float* Kb = Kpad + d;                               // + row*D_
    float*       yb = y + ((size_t)b * L_ + kk * T_) * D_ + d;

    float* const stg0 = smem + (h << 1) * 4096;               // this half's bufs
    float* const stg1 = stg0 + 4096;

    // ---- FIR state (verified indexing from rounds 3/4) -------------------
    float W[16];
    W[0] = 0.f;
    #pragma unroll
    for (int j = 1; j < 16; ++j) W[j] = Kb[(r0 - sA + j) * D_];
    float kr[RING];
    #pragma unroll
    for (int p = 0; p < RING; ++p) kr[p] = Kb[(r0 - sA - p) * D_];
    float acc[16];
    #pragma unroll
    for (int j = 0; j < 16; ++j) acc[j] = 0.f;

    // ---- staging prologue: chunk c0 into regs ----------------------------
    float4 ld[4];
    {
        const float* src = ub + (size_t)sA * D_;
        #pragma unroll
        for (int q = 0; q < 4; ++q)
            ld[q] = *(const float4*)(src + q * 1024 + d * 4);
    }

    for (int cc = 0; cc < Cmax; ++cc) {
        const int c = c0 + cc;
        float* const buf = (cc & 1) ? stg1 : stg0;

        __syncthreads();                       // buf free (prev consumers done)
        #pragma unroll
        for (int q = 0; q < 4; ++q)            // commit staged regs -> LDS
            *(float4*)(buf + q * 1024 + d * 4) = ld[q];

        if (cc + 1 < Cmax) {                   // issue next chunk's loads now
            const float* src = ub + (size_t)((c + 1) * T_) * D_;
            #pragma unroll
            for (int q = 0; q < 4; ++q)
                ld[q] = *(const float4*)(src + q * 1024 + d * 4);
        }
        __syncthreads();                       // buf ready

        if (c < c1) {                          // wave-uniform predicate
            const float* ulds = buf + d;
            const int s0_ = c * T_;
            #pragma unroll
            for (int m = 0; m < 16; ++m) {
                const float uv = ulds[m * D_];
                const float kv = kr[m & (RING - 1)];
                acc[0] = fmaf(kv, uv, acc[0]);
                #pragma unroll
                for (int j = 1; j < 16; ++j)
                    acc[j] = fmaf(W[(j - m) & 15], uv, acc[j]);
                W[(16 - m) & 15] = kv;
                kr[m & (RING - 1)] = Kb[(r0 - (s0_ + m) - RING) * D_];
            }
        }
    }

    // ---- combine halves (part[] aliased over dead staging LDS) -----------
    __syncthreads();
    float* const part = smem;                  // [256][17], 17.4 KB
    if (h == 1) {
        #pragma unroll
        for (int j = 0; j < 16; ++j) part[d * 17 + j] = acc[j];
    }
    __syncthreads();
    if (h == 0) {
        #pragma unroll
        for (int j = 0; j < 16; ++j)
            yb[j * D_] = acc[j] + part[d * 17 + j];
    }
}

extern "C" void kernel_launch(void* const* d_in, const int* in_sizes, int n_in,
                              void* d_out, int out_size, void* d_ws, size_t ws_size,
                              hipStream_t stream) {
    const float* u     = (const float*)d_in[0];
    const float* Lre   = (const float*)d_in[1];
    const float* Lim   = (const float*)d_in[2];
    const float* Bre   = (const float*)d_in[3];
    const float* Bim   = (const float*)d_in[4];
    const float* Pre   = (const float*)d_in[5];
    const float* Pim   = (const float*)d_in[6];
    const float* logdt = (const float*)d_in[7];
    float* y = (float*)d_out;

    float* Kpad0 = (float*)d_ws;             // GUARD rows live here
    float* Kpad  = Kpad0 + GUARD * D_;       // row 0 of the real table

    build_K<<<KROWS, 256, 0, stream>>>(Lre, Lim, Bre, Bim, Pre, Pim, logdt, Kpad);
    conv_fir<<<B_ * NT, 512, 0, stream>>>(u, Kpad, y);
}

// Round 6
// 38.039 us; speedup vs baseline: 2.1972x; 2.1972x over previous
//
#include <hip/hip_runtime.h>

#define BATCH  16
#define LEN    512
#define NSTATE 64
#define DMODEL 256
#define TB     32      // time-batch between wave-private transpose-reduces
#define WAVES  4       // waves per block (4 adjacent d -> merged y writes)
#define PAD    1       // row stride 33: write 2-way (free), read 2-way (free)

__global__ __launch_bounds__(WAVES * 64, 4)
void s4d_scan_kernel(const float* __restrict__ u,
                     const float* __restrict__ Lre_p, const float* __restrict__ Lim_p,
                     const float* __restrict__ Bre_p, const float* __restrict__ Bim_p,
                     const float* __restrict__ Pre_p, const float* __restrict__ Pim_p,
                     const float* __restrict__ logdt_p,
                     float* __restrict__ y)
{
    // WAVE-PRIVATE slab: each wave writes AND reads only cb[widx] -> NO
    // __syncthreads() anywhere (same-wave LDS ordering via lgkmcnt).
    __shared__ float cb[WAVES][NSTATE][TB + PAD];   // 4*64*33*4 = 33.8 KB

    const int tid  = threadIdx.x;
    const int lane = tid & 63;
    const int widx = tid >> 6;
    const int wid  = blockIdx.x * WAVES + widx;   // 0..4095
    const int b    = wid >> 8;                    // / DMODEL
    const int d    = wid & 255;                   // % DMODEL

    // ---- per-lane (state n = lane) coefficients --------------------------
    const float dt  = expf(logdt_p[0]);
    const float Lre = Lre_p[lane];
    const float Lim = Lim_p[lane];
    const float eL  = expf(Lre);
    const float wre = -eL * cosf(Lim);            // w = -exp(Lambda)
    const float wim = -eL * sinf(Lim);
    const float mag = expf(dt * wre);             // a = exp(dt*w)
    const float are = mag * cosf(dt * wim);
    const float aim = mag * sinf(dt * wim);
    const float Bdre = dt * Bre_p[lane];
    const float Bdim = dt * Bim_p[lane];
    const float Pre  = Pre_p[lane * DMODEL + d];
    const float Pim  = Pim_p[lane * DMODEL + d];
    const float Gre = Pre * Bdre - Pim * Bdim;    // G = C*Bd (fold projection)
    const float Gim = Pre * Bdim + Pim * Bdre;

    float zre = 0.f, zim = 0.f;                   // z = C*x per state

    const float* up = u + (size_t)b * LEN * DMODEL + d;   // + t*DMODEL
    float*       yp = y + (size_t)b * LEN * DMODEL + d;

    const int tl = lane & 31;     // reduce column (time slot)
    const int h  = lane >> 5;     // state-half this lane reduces

    // prefetch macro-batch 0: 64 timesteps, one per lane
    float ucur = up[lane * DMODEL];

    for (int m = 0; m < LEN / 64; ++m) {
        // issue next macro-batch load now (branchless wrap on last iter;
        // the wrapped values are never consumed)
        const int mn = (m + 1) & (LEN / 64 - 1);
        float unext = up[(mn * 64 + lane) * DMODEL];

        #pragma unroll
        for (int half = 0; half < 2; ++half) {
            #pragma unroll
            for (int tau = 0; tau < TB; tau += 2) {
                const float us0 = __uint_as_float(
                    __builtin_amdgcn_readlane(__float_as_uint(ucur), half * 32 + tau));
                const float r0 = fmaf(are, zre, fmaf(-aim, zim, Gre * us0));
                const float i0 = fmaf(are, zim, fmaf( aim, zre, Gim * us0));
                const float us1 = __uint_as_float(
                    __builtin_amdgcn_readlane(__float_as_uint(ucur), half * 32 + tau + 1));
                const float r1 = fmaf(are, r0, fmaf(-aim, i0, Gre * us1));
                const float i1 = fmaf(are, i0, fmaf( aim, r0, Gim * us1));
                zre = r1; zim = i1;
                cb[widx][lane][tau]     = r0;      // paired adjacent stores
                cb[widx][lane][tau + 1] = r1;
            }

            // wave-private transpose-reduce (no barrier!):
            // lane (h, tl) sums states 32h..32h+31 at time slot tl
            float s0 = 0.f, s1 = 0.f, s2 = 0.f, s3 = 0.f;
            #pragma unroll
            for (int j = 0; j < 32; j += 4) {      // 4 partials: short dep chain
                s0 += cb[widx][32 * h + j + 0][tl];
                s1 += cb[widx][32 * h + j + 1][tl];
                s2 += cb[widx][32 * h + j + 2][tl];
                s3 += cb[widx][32 * h + j + 3][tl];
            }
            float s = (s0 + s1) + (s2 + s3);
            s += __shfl_xor(s, 32, 64);            // combine state-halves
            if (lane < 32)
                yp[(m * 64 + half * 32 + tl) * DMODEL] = s;
        }
        ucur = unext;
    }
}

extern "C" void kernel_launch(void* const* d_in, const int* in_sizes, int n_in,
                              void* d_out, int out_size, void* d_ws, size_t ws_size,
                              hipStream_t stream) {
    const float* u      = (const float*)d_in[0];
    const float* Lre    = (const float*)d_in[1];
    const float* Lim    = (const float*)d_in[2];
    const float* Bre    = (const float*)d_in[3];
    const float* Bim    = (const float*)d_in[4];
    const float* Pre    = (const float*)d_in[5];
    const float* Pim    = (const float*)d_in[6];
    const float* logdt  = (const float*)d_in[7];
    float* y = (float*)d_out;

    const int nblocks = (BATCH * DMODEL) / WAVES;   // 1024
    s4d_scan_kernel<<<nblocks, WAVES * 64, 0, stream>>>(
        u, Lre, Lim, Bre, Bim, Pre, Pim, logdt, y);
}